// Round 1
// baseline (1216.524 us; speedup 1.0000x reference)
//
#include <hip/hip_runtime.h>
#include <hip/hip_bf16.h>

// ---------------------------------------------------------------------------
// Problem constants
#define DIM   4096
#define NH    32
#define NKV   8
#define HD    128
#define INTER 14336
#define PS    16
#define B     32
#define QKV_N ((NH + 2*NKV) * HD)   // 6144
#define EPS   1e-5f
#define LOG2E 1.4426950408889634f

typedef float  f32x4  __attribute__((ext_vector_type(4)));
typedef short  bf16x8 __attribute__((ext_vector_type(8)));

#define LD4(p) (*(const f32x4*)(p))

__device__ __forceinline__ short f2bf(float f) {
    unsigned u = __builtin_bit_cast(unsigned, f);
    u += 0x7fffu + ((u >> 16) & 1u);          // round-to-nearest-even
    return (short)(u >> 16);
}

__device__ __forceinline__ bf16x8 cvt8(f32x4 lo, f32x4 hi) {
    bf16x8 r;
    r[0]=f2bf(lo[0]); r[1]=f2bf(lo[1]); r[2]=f2bf(lo[2]); r[3]=f2bf(lo[3]);
    r[4]=f2bf(hi[0]); r[5]=f2bf(hi[1]); r[6]=f2bf(hi[2]); r[7]=f2bf(hi[3]);
    return r;
}

__device__ __forceinline__ float block_reduce_sum256(float ss) {
    __shared__ float sred[4];
    #pragma unroll
    for (int off = 32; off > 0; off >>= 1) ss += __shfl_xor(ss, off);
    int wid = threadIdx.x >> 6;
    if ((threadIdx.x & 63) == 0) sred[wid] = ss;
    __syncthreads();
    return sred[0] + sred[1] + sred[2] + sred[3];
}

// ---------------------------------------------------------------------------
// K1 / K6 helper-style rmsnorm over 4096-wide rows, 1 block per row
__global__ __launch_bounds__(256) void rmsnorm_kernel(
    const float* __restrict__ x, const float* __restrict__ w,
    float* __restrict__ out)
{
    int b = blockIdx.x;
    const float* xr = x + (size_t)b * DIM;
    float v[16]; float ss = 0.f;
    #pragma unroll
    for (int i = 0; i < 16; ++i) { v[i] = xr[threadIdx.x + 256*i]; ss += v[i]*v[i]; }
    ss = block_reduce_sum256(ss);
    float inv = rsqrtf(ss * (1.f/DIM) + EPS);
    #pragma unroll
    for (int i = 0; i < 16; ++i) {
        int idx = threadIdx.x + 256*i;
        out[(size_t)b*DIM + idx] = v[i] * inv * w[idx];
    }
}

// ---------------------------------------------------------------------------
// Skinny GEMM: C[32,N] = X[32,K] @ W[N,K]^T  (bf16 MFMA, fp32 accum)
// grid = (N/16, KSPLIT), block = 64.  Writes partials P[ks][32][N].
__global__ __launch_bounds__(64) void gemm_skinny(
    const float* __restrict__ X, const float* __restrict__ W,
    float* __restrict__ P, int K, int N, int krange)
{
    const int lane = threadIdx.x;
    const int m = lane & 15;
    const int q = lane >> 4;
    const int nbase = blockIdx.x * 16;
    const long k0 = (long)blockIdx.y * krange + q * 8;
    const float* xr0 = X + (long)m * K + k0;
    const float* xr1 = X + (long)(m + 16) * K + k0;
    const float* wr  = W + (long)(nbase + m) * K + k0;

    f32x4 acc0 = {0.f,0.f,0.f,0.f}, acc1 = {0.f,0.f,0.f,0.f};
    const int iters = krange >> 5;   // 32 k per iter

    f32x4 a0l = LD4(xr0),   a0h = LD4(xr0+4);
    f32x4 a1l = LD4(xr1),   a1h = LD4(xr1+4);
    f32x4 bl  = LD4(wr),    bh  = LD4(wr+4);

    for (int i = 0; i < iters; ++i) {
        int nxt = (i + 1 < iters) ? (i + 1) * 32 : 0;
        f32x4 na0l = LD4(xr0+nxt), na0h = LD4(xr0+nxt+4);
        f32x4 na1l = LD4(xr1+nxt), na1h = LD4(xr1+nxt+4);
        f32x4 nbl  = LD4(wr +nxt), nbh  = LD4(wr +nxt+4);
        bf16x8 af0 = cvt8(a0l, a0h);
        bf16x8 af1 = cvt8(a1l, a1h);
        bf16x8 bf  = cvt8(bl,  bh);
        acc0 = __builtin_amdgcn_mfma_f32_16x16x32_bf16(af0, bf, acc0, 0, 0, 0);
        acc1 = __builtin_amdgcn_mfma_f32_16x16x32_bf16(af1, bf, acc1, 0, 0, 0);
        a0l=na0l; a0h=na0h; a1l=na1l; a1h=na1h; bl=nbl; bh=nbh;
    }
    // C/D layout: col = lane&15, row = (lane>>4)*4 + reg
    float* pb = P + (size_t)blockIdx.y * 32 * N + nbase + m;
    #pragma unroll
    for (int r = 0; r < 4; ++r) {
        pb[(size_t)(q*4 + r) * N]      = acc0[r];
        pb[(size_t)(16 + q*4 + r) * N] = acc1[r];
    }
}

// ---------------------------------------------------------------------------
// K3: reduce QKV partials, RoPE q/k, write q buffer + append k/v to paged KV
// grid = (B, 48 heads), block = 64 (lane = freq index d in [0,64))
__global__ __launch_bounds__(64) void qkv_epilogue(
    const float* __restrict__ P, const int* __restrict__ offsets,
    const int* __restrict__ page_idx, const int* __restrict__ page_indptr,
    const int* __restrict__ lastlen,
    float* __restrict__ Qb, float* __restrict__ pk, float* __restrict__ pv)
{
    int b = blockIdx.x, h = blockIdx.y, d = threadIdx.x;
    int c1 = h*HD + d, c2 = c1 + 64;
    const float* pb = P + (size_t)b * QKV_N;
    float v1 = 0.f, v2 = 0.f;
    #pragma unroll
    for (int ks = 0; ks < 4; ++ks) {
        v1 += pb[(size_t)ks * 32 * QKV_N + c1];
        v2 += pb[(size_t)ks * 32 * QKV_N + c2];
    }
    float o1 = v1, o2 = v2;
    if (h < NH + NKV) {   // rope for q and k heads
        float pos = (float)offsets[b];
        float inv_freq = powf(10000.0f, -(float)d * (1.0f/64.0f));
        float ang = pos * inv_freq;
        float c = cosf(ang), s = sinf(ang);
        o1 = v1*c - v2*s;
        o2 = v1*s + v2*c;
    }
    if (h < NH) {
        Qb[(size_t)b*DIM + c1]      = o1;
        Qb[(size_t)b*DIM + c1 + 64] = o2;
    } else {
        int kvh = (h < NH + NKV) ? (h - NH) : (h - NH - NKV);
        float* dst = (h < NH + NKV) ? pk : pv;
        int page = page_idx[page_indptr[b+1] - 1];
        int slot = lastlen[b] - 1;
        size_t base = (((size_t)page * PS + slot) * NKV + kvh) * HD + d;
        dst[base]      = o1;
        dst[base + 64] = o2;
    }
}

// ---------------------------------------------------------------------------
// K4: flash-decode GQA attention. grid = 256 = (b, kvh), block = 1024 (16 waves)
#define ATT_WAVES 16
__global__ __launch_bounds__(1024) void attn_kernel(
    const float* __restrict__ Qb, const float* __restrict__ pk,
    const float* __restrict__ pv, const int* __restrict__ page_idx,
    const int* __restrict__ page_indptr, const int* __restrict__ lastlen,
    float* __restrict__ Ob)
{
    const int b   = blockIdx.x >> 3;
    const int kvh = blockIdx.x & 7;
    const int tid  = threadIdx.x;
    const int wid  = tid >> 6;
    const int lane = tid & 63;
    const int i3   = lane & 3;

    const int p0  = page_indptr[b];
    const int npg = page_indptr[b+1] - p0;
    const int kv_len = (npg - 1) * PS + lastlen[b];

    const float scale2 = LOG2E / 11.313708498984761f;  // log2(e)/sqrt(128)
    float2 qv[4];
    #pragma unroll
    for (int g = 0; g < 4; ++g) {   // natural head order — uniform across lanes
        const float* qp = Qb + (size_t)b*DIM + (kvh*4 + g)*HD + 2*lane;
        qv[g].x = qp[0] * scale2; qv[g].y = qp[1] * scale2;
    }
    float mj[4] = {-1e30f,-1e30f,-1e30f,-1e30f};
    float lj[4] = {0.f,0.f,0.f,0.f};
    float ox[4] = {0.f,0.f,0.f,0.f};
    float oy[4] = {0.f,0.f,0.f,0.f};

    #pragma unroll 2
    for (int t = wid; t < kv_len; t += ATT_WAVES) {
        int page = page_idx[p0 + (t >> 4)];
        size_t base = (((size_t)page * PS + (t & 15)) * NKV + kvh) * HD + 2*lane;
        float2 k2 = *(const float2*)(pk + base);
        float2 v2 = *(const float2*)(pv + base);
        float pd[4];
        #pragma unroll
        for (int g = 0; g < 4; ++g)
            pd[g] = fmaf(qv[g].x, k2.x, qv[g].y * k2.y);
        // permuted butterfly: after this, r = full 64-lane sum for head (lane&3)
        bool b1 = (lane & 1) != 0, b2 = (lane & 2) != 0;
        float u  = b1 ? pd[1] : pd[0];
        float vv = b1 ? pd[0] : pd[1];
        u += __shfl_xor(vv, 1);
        float w_ = b1 ? pd[3] : pd[2];
        float z  = b1 ? pd[2] : pd[3];
        w_ += __shfl_xor(z, 1);
        float r = b2 ? w_ : u;
        float s = b2 ? u  : w_;
        r += __shfl_xor(s, 2);
        r += __shfl_xor(r, 4);
        r += __shfl_xor(r, 8);
        r += __shfl_xor(r, 16);
        r += __shfl_xor(r, 32);
        float sA = __shfl_xor(r, 1);
        float sB = __shfl_xor(r, 2);
        float sC = __shfl_xor(sA, 2);
        float sj[4] = {r, sA, sB, sC};   // sj[j] = score of head (i3^j)
        #pragma unroll
        for (int j = 0; j < 4; ++j) {
            float mn = fmaxf(mj[j], sj[j]);
            float al = exp2f(mj[j] - mn);
            float pe = exp2f(sj[j] - mn);
            mj[j] = mn;
            lj[j] = lj[j]*al + pe;
            ox[j] = ox[j]*al + pe*v2.x;
            oy[j] = oy[j]*al + pe*v2.y;
        }
    }
    __shared__ float sO[ATT_WAVES][4][HD];
    __shared__ float sM[ATT_WAVES][4];
    __shared__ float sL[ATT_WAVES][4];
    #pragma unroll
    for (int j = 0; j < 4; ++j) {
        int g = i3 ^ j;
        sO[wid][g][2*lane]   = ox[j];
        sO[wid][g][2*lane+1] = oy[j];
    }
    if (i3 == 0) {
        #pragma unroll
        for (int j = 0; j < 4; ++j) { sM[wid][j] = mj[j]; sL[wid][j] = lj[j]; }
    }
    __syncthreads();
    if (tid < 512) {
        int g = tid >> 7, d = tid & 127;
        float M = -1e30f;
        #pragma unroll
        for (int w = 0; w < ATT_WAVES; ++w) M = fmaxf(M, sM[w][g]);
        float Ls = 0.f, acc = 0.f;
        #pragma unroll
        for (int w = 0; w < ATT_WAVES; ++w) {
            float sc = exp2f(sM[w][g] - M);
            Ls  += sL[w][g] * sc;
            acc += sO[w][g][d] * sc;
        }
        Ob[(size_t)b*DIM + (kvh*4 + g)*HD + d] = acc / Ls;
    }
}

// ---------------------------------------------------------------------------
// K6: h = x + sum(Pwo) ; hf = rmsnorm(h, ffn_w).  1 block per row.
__global__ __launch_bounds__(256) void h_rms_kernel(
    const float* __restrict__ x, const float* __restrict__ P,
    const float* __restrict__ w, float* __restrict__ H, float* __restrict__ HF)
{
    int b = blockIdx.x;
    float v[16]; float ss = 0.f;
    #pragma unroll
    for (int i = 0; i < 16; ++i) {
        int idx = threadIdx.x + 256*i;
        size_t col = (size_t)b*DIM + idx;
        float t = x[col];
        #pragma unroll
        for (int ks = 0; ks < 4; ++ks) t += P[(size_t)ks * 32 * DIM + col];
        v[i] = t; ss += t*t; H[col] = t;
    }
    ss = block_reduce_sum256(ss);
    float inv = rsqrtf(ss * (1.f/DIM) + EPS);
    #pragma unroll
    for (int i = 0; i < 16; ++i) {
        int idx = threadIdx.x + 256*i;
        HF[(size_t)b*DIM + idx] = v[i] * inv * w[idx];
    }
}

// K8: hidden = silu(sum(Pw1)) * stem(buffer gather)
__global__ __launch_bounds__(256) void hidden_kernel(
    const float* __restrict__ P, const float* __restrict__ buffer,
    const int* __restrict__ bids, float* __restrict__ HID)
{
    int b = blockIdx.x;
    int i = blockIdx.y * 256 + threadIdx.x;
    size_t col = (size_t)b * INTER + i;
    float vx = P[col] + P[(size_t)32 * INTER + col];
    float sg = 1.0f / (1.0f + exp2f(-vx * LOG2E));
    float stem = buffer[(size_t)bids[b] * INTER + i];
    HID[col] = vx * sg * stem;
}

// K10: out = h + sum(Pw2)
__global__ __launch_bounds__(256) void final_kernel(
    const float* __restrict__ H, const float* __restrict__ P,
    float* __restrict__ out)
{
    int b = blockIdx.x;
    int i = blockIdx.y * 256 + threadIdx.x;
    size_t col = (size_t)b * DIM + i;
    float v = H[col];
    #pragma unroll
    for (int ks = 0; ks < 8; ++ks) v += P[(size_t)ks * 32 * DIM + col];
    out[col] = v;
}

// ---------------------------------------------------------------------------
extern "C" void kernel_launch(void* const* d_in, const int* in_sizes, int n_in,
                              void* d_out, int out_size, void* d_ws, size_t ws_size,
                              hipStream_t stream)
{
    const float* x        = (const float*)d_in[0];
    const float* buffer   = (const float*)d_in[1];
    float*       paged_k  = (float*)d_in[2];   // written with k_new (restored each launch)
    float*       paged_v  = (float*)d_in[3];
    const float* wqkv     = (const float*)d_in[4];
    const float* wo       = (const float*)d_in[5];
    const float* w1       = (const float*)d_in[6];
    const float* w2       = (const float*)d_in[7];
    const float* attn_w   = (const float*)d_in[8];
    const float* ffn_w    = (const float*)d_in[9];
    const int*   bids     = (const int*)d_in[10];
    const int*   offsets  = (const int*)d_in[11];
    const int*   pg_idx   = (const int*)d_in[13];
    const int*   pg_iptr  = (const int*)d_in[14];
    const int*   pg_last  = (const int*)d_in[15];
    float* out = (float*)d_out;

    // workspace layout (floats)
    float* ws   = (float*)d_ws;
    float* XA   = ws;                       // 32*4096
    float* PQKV = XA   + 32*DIM;            // 4*32*6144
    float* Qb   = PQKV + 4*32*QKV_N;        // 32*4096
    float* Ob   = Qb   + 32*DIM;            // 32*4096
    float* PWO  = Ob   + 32*DIM;            // 4*32*4096
    float* Hb   = PWO  + 4*32*DIM;          // 32*4096
    float* HF   = Hb   + 32*DIM;            // 32*4096
    float* PW1  = HF   + 32*DIM;            // 2*32*14336
    float* HID  = PW1  + 2*32*INTER;        // 32*14336
    float* PW2  = HID  + 32*INTER;          // 8*32*4096

    // 1. xa = rmsnorm(x)
    rmsnorm_kernel<<<B, 256, 0, stream>>>(x, attn_w, XA);
    // 2. qkv partials
    gemm_skinny<<<dim3(QKV_N/16, 4), 64, 0, stream>>>(XA, wqkv, PQKV, DIM, QKV_N, DIM/4);
    // 3. reduce + rope + kv append
    qkv_epilogue<<<dim3(B, 48), 64, 0, stream>>>(PQKV, offsets, pg_idx, pg_iptr, pg_last,
                                                 Qb, paged_k, paged_v);
    // 4. attention
    attn_kernel<<<B*NKV, 1024, 0, stream>>>(Qb, paged_k, paged_v, pg_idx, pg_iptr, pg_last, Ob);
    // 5. wo partials
    gemm_skinny<<<dim3(DIM/16, 4), 64, 0, stream>>>(Ob, wo, PWO, DIM, DIM, DIM/4);
    // 6. h = x + o@wo^T ; hf = rmsnorm(h)
    h_rms_kernel<<<B, 256, 0, stream>>>(x, PWO, ffn_w, Hb, HF);
    // 7. w1 partials
    gemm_skinny<<<dim3(INTER/16, 2), 64, 0, stream>>>(HF, w1, PW1, DIM, INTER, DIM/2);
    // 8. hidden = silu(.)*stem
    hidden_kernel<<<dim3(B, INTER/256), 256, 0, stream>>>(PW1, buffer, bids, HID);
    // 9. w2 partials
    gemm_skinny<<<dim3(DIM/16, 8), 64, 0, stream>>>(HID, w2, PW2, INTER, DIM, INTER/8);
    // 10. out = h + y
    final_kernel<<<dim3(B, DIM/256), 256, 0, stream>>>(Hb, PW2, out);
}